// Round 2
// baseline (280.950 us; speedup 1.0000x reference)
//
#include <hip/hip_runtime.h>

#define CDIM 512
#define NH 8
#define HWDIM 4096
#define BATCH 16

// ---------------- prep: fold weights ----------------
// wvT[c*8+n] = sum_j wqkv[(1024+64n+j)*512 + c]   (4096 floats)
// wp [o*8+n] = sum_j wproj[o*512 + 64n + j]       (4096 floats)
__global__ __launch_bounds__(256) void prep_kernel(
    const float* __restrict__ wqkv, const float* __restrict__ wproj,
    float* __restrict__ wvT, float* __restrict__ wp) {
  int idx = blockIdx.x * 256 + threadIdx.x;
  if (idx < 4096) {
    int n = idx >> 9, c = idx & 511;           // consecutive threads -> consecutive c (coalesced)
    const float* p = wqkv + (size_t)(1024 + n * 64) * CDIM + c;
    float s = 0.f;
#pragma unroll 8
    for (int j = 0; j < 64; ++j) s += p[(size_t)j * CDIM];
    wvT[c * 8 + n] = s;
  } else if (idx < 8192) {
    int i2 = idx - 4096;
    int n = i2 >> 9, o = i2 & 511;
    const float* p = wproj + (size_t)o * CDIM + n * 64;
    float s = 0.f;
#pragma unroll 4
    for (int j = 0; j < 16; ++j) {
      float4 v = *(const float4*)(p + j * 4);
      s += v.x + v.y + v.z + v.w;
    }
    wp[o * 8 + n] = s;
  }
}

// ---------------- kernel S: S[b,n,s] = sum_c wvT[c,n] * x[b,c,s] ----------------
// grid 1024 x 256. Block owns 64 positions (16 float4). 16 channel-groups of 32.
__global__ __launch_bounds__(256) void s_kernel(
    const float* __restrict__ x, const float* __restrict__ wvT,
    float* __restrict__ S) {
  __shared__ __align__(16) float sPart[4][NH][64];   // 8 KB

  const int t = threadIdx.x;
  const int wave = t >> 6;
  const int lane = t & 63;
  const int f = lane & 15;          // float4 index within 64-pos tile
  const int sub = lane >> 4;        // 0..3
  const int cg = wave * 4 + sub;    // 0..15 -> 32 channels each

  const int pos0 = blockIdx.x * 64;
  const int b = pos0 >> 12;
  const int hw0 = pos0 & (HWDIM - 1);

  const float* xb = x + ((size_t)b * CDIM + (size_t)cg * 32) * HWDIM + hw0 + f * 4;
  const float* wb = wvT + cg * 32 * 8;

  float acc[NH][4];
#pragma unroll
  for (int n = 0; n < NH; ++n)
    acc[n][0] = acc[n][1] = acc[n][2] = acc[n][3] = 0.f;

#pragma unroll 8
  for (int cc = 0; cc < 32; ++cc) {
    const float4 xv = *(const float4*)(xb + (size_t)cc * HWDIM);
    const float4 w0 = *(const float4*)(wb + cc * 8);
    const float4 w1 = *(const float4*)(wb + cc * 8 + 4);
    const float wn[8] = {w0.x, w0.y, w0.z, w0.w, w1.x, w1.y, w1.z, w1.w};
    const float xv4[4] = {xv.x, xv.y, xv.z, xv.w};
#pragma unroll
    for (int n = 0; n < NH; ++n)
#pragma unroll
      for (int p = 0; p < 4; ++p) acc[n][p] = fmaf(wn[n], xv4[p], acc[n][p]);
  }

  // reduce over lane bits 4,5 (the 4 sub-groups within the wave)
#pragma unroll
  for (int n = 0; n < NH; ++n)
#pragma unroll
    for (int p = 0; p < 4; ++p) {
      float v = acc[n][p];
      v += __shfl_xor(v, 16, 64);
      v += __shfl_xor(v, 32, 64);
      acc[n][p] = v;
    }

  if (sub == 0) {
#pragma unroll
    for (int n = 0; n < NH; ++n)
      *(float4*)&sPart[wave][n][f * 4] =
          make_float4(acc[n][0], acc[n][1], acc[n][2], acc[n][3]);
  }
  __syncthreads();

  // 512 outputs (n, sp); 256 threads x 2
#pragma unroll
  for (int r = 0; r < 2; ++r) {
    const int v = t + r * 256;
    const int n = v >> 6, sp = v & 63;
    const float s =
        sPart[0][n][sp] + sPart[1][n][sp] + sPart[2][n][sp] + sPart[3][n][sp];
    S[(size_t)b * NH * HWDIM + (size_t)n * HWDIM + hw0 + sp] = s;
  }
}

// ---------------- kernel Y: y[b,o,s] = bias[o] + sum_n wp[o,n] * S[b,n,s] ----------------
// grid 1024 x 256. Block owns 64 positions; 16 output-groups of 32 outputs.
__global__ __launch_bounds__(256) void y_kernel(
    const float* __restrict__ S, const float* __restrict__ wp,
    const float* __restrict__ bias, float* __restrict__ y) {
  const int t = threadIdx.x;
  const int wave = t >> 6;
  const int lane = t & 63;
  const int f = lane & 15;
  const int og = wave * 4 + (lane >> 4);   // 0..15 -> 32 outputs each

  const int pos0 = blockIdx.x * 64;
  const int b = pos0 >> 12;
  const int hw0 = pos0 & (HWDIM - 1);

  float4 Sv[NH];
#pragma unroll
  for (int n = 0; n < NH; ++n)
    Sv[n] = *(const float4*)(S + (size_t)b * NH * HWDIM + (size_t)n * HWDIM + hw0 + f * 4);

  float* yb = y + ((size_t)b * CDIM + (size_t)og * 32) * HWDIM + hw0 + f * 4;
  const float* wb = wp + og * 32 * 8;
  const float* bb = bias + og * 32;

#pragma unroll 4
  for (int i = 0; i < 32; ++i) {
    const float4 w0 = *(const float4*)(wb + i * 8);
    const float4 w1 = *(const float4*)(wb + i * 8 + 4);
    const float wn[8] = {w0.x, w0.y, w0.z, w0.w, w1.x, w1.y, w1.z, w1.w};
    const float b0 = bb[i];
    float r[4] = {b0, b0, b0, b0};
#pragma unroll
    for (int n = 0; n < NH; ++n) {
      r[0] = fmaf(wn[n], Sv[n].x, r[0]);
      r[1] = fmaf(wn[n], Sv[n].y, r[1]);
      r[2] = fmaf(wn[n], Sv[n].z, r[2]);
      r[3] = fmaf(wn[n], Sv[n].w, r[3]);
    }
    *(float4*)(yb + (size_t)i * HWDIM) = make_float4(r[0], r[1], r[2], r[3]);
  }
}

extern "C" void kernel_launch(void* const* d_in, const int* in_sizes, int n_in,
                              void* d_out, int out_size, void* d_ws, size_t ws_size,
                              hipStream_t stream) {
  const float* x     = (const float*)d_in[0];
  const float* wqkv  = (const float*)d_in[1];
  const float* wproj = (const float*)d_in[2];
  const float* bproj = (const float*)d_in[3];
  float* y = (float*)d_out;

  float* wvT = (float*)d_ws;                 // 4096 floats
  float* wp  = wvT + 4096;                   // 4096 floats
  float* S   = wp + 4096;                    // 16*8*4096 = 524288 floats (2 MB)

  prep_kernel<<<32, 256, 0, stream>>>(wqkv, wproj, wvT, wp);
  s_kernel<<<1024, 256, 0, stream>>>(x, wvT, S);
  y_kernel<<<1024, 256, 0, stream>>>(S, wp, bproj, y);
}

// Round 3
// 280.842 us; speedup vs baseline: 1.0004x; 1.0004x over previous
//
#include <hip/hip_runtime.h>

#define CDIM 512
#define NH 8
#define HWDIM 4096
#define BATCH 16
#define PTILE 256          // spatial positions per block -> 1 KB granules
#define PSTRIDE (BATCH * NH * HWDIM)   // floats per S-partial (2 MB)

// ---------------- prep: fold weights ----------------
// wvT[c*8+n] = sum_j wqkv[(1024+64n+j)*512 + c]   (4096 floats)
// wp [o*8+n] = sum_j wproj[o*512 + 64n + j]       (4096 floats)
__global__ __launch_bounds__(256) void prep_kernel(
    const float* __restrict__ wqkv, const float* __restrict__ wproj,
    float* __restrict__ wvT, float* __restrict__ wp) {
  int idx = blockIdx.x * 256 + threadIdx.x;
  if (idx < 4096) {
    int n = idx >> 9, c = idx & 511;   // consecutive threads -> consecutive c
    const float* p = wqkv + (size_t)(1024 + n * 64) * CDIM + c;
    float s = 0.f;
#pragma unroll 8
    for (int j = 0; j < 64; ++j) s += p[(size_t)j * CDIM];
    wvT[c * 8 + n] = s;
  } else if (idx < 8192) {
    int i2 = idx - 4096;
    int n = i2 >> 9, o = i2 & 511;
    const float* p = wproj + (size_t)o * CDIM + n * 64;
    float s = 0.f;
#pragma unroll 4
    for (int j = 0; j < 16; ++j) {
      float4 v = *(const float4*)(p + j * 4);
      s += v.x + v.y + v.z + v.w;
    }
    wp[o * 8 + n] = s;
  }
}

// ---------------- s_part: pS[cg][b,n,s] = sum_{c in cg} wvT[c,n] * x[b,c,s] ----------
// grid 1024 = 256 pos-tiles x 4 channel-groups. Block: 256 positions, 128 channels.
__global__ __launch_bounds__(256, 4) void s_part_kernel(
    const float* __restrict__ x, const float* __restrict__ wvT,
    float* __restrict__ pS) {
  __shared__ __align__(16) float sPart[4][NH][PTILE];   // 32 KB

  const int t = threadIdx.x;
  const int wave = t >> 6;
  const int lane = t & 63;
  const int bx = blockIdx.x;
  const int pt = bx & 255;          // pos-tile: consecutive blocks stream positions
  const int cg = bx >> 8;           // 0..3
  const int b = pt >> 4;
  const int hw0 = (pt & 15) << 8;

  const int c0 = cg * 128 + wave * 32;
  const float* xb = x + ((size_t)b * CDIM + c0) * HWDIM + hw0 + lane * 4;
  const float* wb = wvT + c0 * 8;

  float acc[NH][4];
#pragma unroll
  for (int n = 0; n < NH; ++n)
    acc[n][0] = acc[n][1] = acc[n][2] = acc[n][3] = 0.f;

#pragma unroll 8
  for (int cc = 0; cc < 32; ++cc) {
    const float4 xv = *(const float4*)(xb + (size_t)cc * HWDIM);  // 1 KB/wave-instr
    const float4 w0 = *(const float4*)(wb + cc * 8);
    const float4 w1 = *(const float4*)(wb + cc * 8 + 4);
    const float wn[8] = {w0.x, w0.y, w0.z, w0.w, w1.x, w1.y, w1.z, w1.w};
    const float xv4[4] = {xv.x, xv.y, xv.z, xv.w};
#pragma unroll
    for (int n = 0; n < NH; ++n)
#pragma unroll
      for (int p = 0; p < 4; ++p) acc[n][p] = fmaf(wn[n], xv4[p], acc[n][p]);
  }

#pragma unroll
  for (int n = 0; n < NH; ++n)
    *(float4*)&sPart[wave][n][lane * 4] =
        make_float4(acc[n][0], acc[n][1], acc[n][2], acc[n][3]);
  __syncthreads();

  // reduce 4 waves, store 8 KB (8 rows x 1 KB contiguous)
  float* out = pS + (size_t)cg * PSTRIDE + ((size_t)b * NH) * HWDIM + hw0;
#pragma unroll
  for (int r = 0; r < 8; ++r) {
    const int i = t + r * 256;
    const int n = i >> 8, sp = i & 255;
    const float v =
        sPart[0][n][sp] + sPart[1][n][sp] + sPart[2][n][sp] + sPart[3][n][sp];
    out[(size_t)n * HWDIM + sp] = v;
  }
}

// ---------------- y: y[b,o,s] = bias[o] + sum_n wp[o,n] * S[b,n,s] ----------------
// grid 1024 = 256 pos-tiles x 4 output-groups. Block: 256 positions, 128 outputs.
__global__ __launch_bounds__(256, 4) void y_kernel(
    const float* __restrict__ pS, const float* __restrict__ wp,
    const float* __restrict__ bias, float* __restrict__ y) {
  const int t = threadIdx.x;
  const int wave = t >> 6;
  const int lane = t & 63;
  const int bx = blockIdx.x;
  const int pt = bx & 255;
  const int og = bx >> 8;
  const int b = pt >> 4;
  const int hw0 = (pt & 15) << 8;

  // gather + reduce the 4 S-partials for this window (L2-hot, 32 KB/block)
  float4 Sv[NH];
#pragma unroll
  for (int n = 0; n < NH; ++n) {
    const float* p = pS + ((size_t)b * NH + n) * HWDIM + hw0 + lane * 4;
    const float4 a0 = *(const float4*)(p);
    const float4 a1 = *(const float4*)(p + PSTRIDE);
    const float4 a2 = *(const float4*)(p + 2 * (size_t)PSTRIDE);
    const float4 a3 = *(const float4*)(p + 3 * (size_t)PSTRIDE);
    Sv[n] = make_float4(a0.x + a1.x + a2.x + a3.x, a0.y + a1.y + a2.y + a3.y,
                        a0.z + a1.z + a2.z + a3.z, a0.w + a1.w + a2.w + a3.w);
  }

  const int o0 = og * 128 + wave * 32;
  const float* wb = wp + o0 * 8;
  const float* bb = bias + o0;
  float* yb = y + ((size_t)b * CDIM + o0) * HWDIM + hw0 + lane * 4;

#pragma unroll 4
  for (int i = 0; i < 32; ++i) {
    const float4 w0 = *(const float4*)(wb + i * 8);
    const float4 w1 = *(const float4*)(wb + i * 8 + 4);
    const float wn[8] = {w0.x, w0.y, w0.z, w0.w, w1.x, w1.y, w1.z, w1.w};
    const float b0 = bb[i];
    float r[4] = {b0, b0, b0, b0};
#pragma unroll
    for (int n = 0; n < NH; ++n) {
      r[0] = fmaf(wn[n], Sv[n].x, r[0]);
      r[1] = fmaf(wn[n], Sv[n].y, r[1]);
      r[2] = fmaf(wn[n], Sv[n].z, r[2]);
      r[3] = fmaf(wn[n], Sv[n].w, r[3]);
    }
    *(float4*)(yb + (size_t)i * HWDIM) = make_float4(r[0], r[1], r[2], r[3]);
  }
}

extern "C" void kernel_launch(void* const* d_in, const int* in_sizes, int n_in,
                              void* d_out, int out_size, void* d_ws, size_t ws_size,
                              hipStream_t stream) {
  const float* x     = (const float*)d_in[0];
  const float* wqkv  = (const float*)d_in[1];
  const float* wproj = (const float*)d_in[2];
  const float* bproj = (const float*)d_in[3];
  float* y = (float*)d_out;

  float* wvT = (float*)d_ws;                 // 4096 floats
  float* wp  = wvT + 4096;                   // 4096 floats
  float* pS  = wp + 4096;                    // 4 x 2 MB partial S

  prep_kernel<<<32, 256, 0, stream>>>(wqkv, wproj, wvT, wp);
  s_part_kernel<<<1024, 256, 0, stream>>>(x, wvT, pS);
  y_kernel<<<1024, 256, 0, stream>>>(pS, wp, bproj, y);
}

// Round 4
// 279.945 us; speedup vs baseline: 1.0036x; 1.0032x over previous
//
#include <hip/hip_runtime.h>

#define CDIM 512
#define NH 8
#define HWDIM 4096
#define BATCH 16
#define PSTRIDE ((size_t)BATCH * NH * HWDIM)   // floats per S-partial (2 MB)

// ---------------- prep: fold weights ----------------
// wvT[c*8+n] = sum_j wqkv[(1024+64n+j)*512 + c]   (4096 floats)
// wp [o*8+n] = sum_j wproj[o*512 + 64n + j]       (4096 floats)
__global__ __launch_bounds__(256) void prep_kernel(
    const float* __restrict__ wqkv, const float* __restrict__ wproj,
    float* __restrict__ wvT, float* __restrict__ wp) {
  int idx = blockIdx.x * 256 + threadIdx.x;
  if (idx < 4096) {
    int n = idx >> 9, c = idx & 511;   // consecutive threads -> consecutive c
    const float* p = wqkv + (size_t)(1024 + n * 64) * CDIM + c;
    float s = 0.f;
#pragma unroll 8
    for (int j = 0; j < 64; ++j) s += p[(size_t)j * CDIM];
    wvT[c * 8 + n] = s;
  } else if (idx < 8192) {
    int i2 = idx - 4096;
    int n = i2 >> 9, o = i2 & 511;
    const float* p = wproj + (size_t)o * CDIM + n * 64;
    float s = 0.f;
#pragma unroll 4
    for (int j = 0; j < 16; ++j) {
      float4 v = *(const float4*)(p + j * 4);
      s += v.x + v.y + v.z + v.w;
    }
    wp[o * 8 + n] = s;
  }
}

// ---------- s_part: pS[cg][b,n,s] = sum_{c in cg} wvT[c,n] * x[b,c,s] ----------
// grid 256 = 64 pos-tiles x 4 channel-groups. Block owns 1024 contiguous
// positions; every channel row is read as one block-wide 4-KB contiguous
// access. Barriers every 16 channels keep the 4 waves' accesses clustered
// (64-KB contiguous DRAM window per epoch).
__global__ __launch_bounds__(256) void s_part_kernel(
    const float* __restrict__ x, const float* __restrict__ wvT,
    float* __restrict__ pS) {
  const int t = threadIdx.x;
  const int bx = blockIdx.x;
  const int pt = bx & 63;           // (b, quarter)
  const int cg = bx >> 6;           // 0..3
  const int b = pt >> 2;
  const int s0 = ((pt & 3) << 10) + t * 4;

  const float* xb = x + ((size_t)b * CDIM + cg * 128) * HWDIM + s0;
  const float* wb = wvT + cg * 128 * 8;

  float acc[NH][4];
#pragma unroll
  for (int n = 0; n < NH; ++n)
    acc[n][0] = acc[n][1] = acc[n][2] = acc[n][3] = 0.f;

  for (int cc0 = 0; cc0 < 128; cc0 += 16) {
#pragma unroll
    for (int half = 0; half < 2; ++half) {
      float4 xv[8];
#pragma unroll
      for (int u = 0; u < 8; ++u)
        xv[u] = *(const float4*)(xb + (size_t)(cc0 + half * 8 + u) * HWDIM);
#pragma unroll
      for (int u = 0; u < 8; ++u) {
        const int c = cc0 + half * 8 + u;
        const float4 w0 = *(const float4*)(wb + c * 8);
        const float4 w1 = *(const float4*)(wb + c * 8 + 4);
        const float wn[8] = {w0.x, w0.y, w0.z, w0.w, w1.x, w1.y, w1.z, w1.w};
        const float xv4[4] = {xv[u].x, xv[u].y, xv[u].z, xv[u].w};
#pragma unroll
        for (int n = 0; n < NH; ++n)
#pragma unroll
          for (int p = 0; p < 4; ++p)
            acc[n][p] = fmaf(wn[n], xv4[p], acc[n][p]);
      }
    }
    __syncthreads();   // keep waves in lockstep -> clustered DRAM window
  }

  // store 8 rows, each a block-wide 4-KB contiguous store
  float* out = pS + (size_t)cg * PSTRIDE + ((size_t)b * NH) * HWDIM + s0;
#pragma unroll
  for (int n = 0; n < NH; ++n)
    *(float4*)(out + (size_t)n * HWDIM) =
        make_float4(acc[n][0], acc[n][1], acc[n][2], acc[n][3]);
}

// ---------- y: y[b,o,s] = bias[o] + sum_n wp[o,n] * sum_cg pS[cg][b,n,s] ----------
// grid 256 = 64 pos-tiles x 4 output-groups. Block owns 1024 contiguous
// positions; each output row written as one block-wide 4-KB contiguous store.
__global__ __launch_bounds__(256) void y_kernel(
    const float* __restrict__ pS, const float* __restrict__ wp,
    const float* __restrict__ bias, float* __restrict__ y) {
  const int t = threadIdx.x;
  const int bx = blockIdx.x;
  const int pt = bx & 63;
  const int og = bx >> 6;
  const int b = pt >> 2;
  const int s0 = ((pt & 3) << 10) + t * 4;

  // reduce the 4 S-partials (L2-hot; each row block-wide 4-KB contiguous)
  float4 Sv[NH];
  const float* base = pS + ((size_t)b * NH) * HWDIM + s0;
#pragma unroll
  for (int n = 0; n < NH; ++n) {
    const float* p = base + (size_t)n * HWDIM;
    const float4 a0 = *(const float4*)(p);
    const float4 a1 = *(const float4*)(p + PSTRIDE);
    const float4 a2 = *(const float4*)(p + 2 * PSTRIDE);
    const float4 a3 = *(const float4*)(p + 3 * PSTRIDE);
    Sv[n] = make_float4(a0.x + a1.x + a2.x + a3.x, a0.y + a1.y + a2.y + a3.y,
                        a0.z + a1.z + a2.z + a3.z, a0.w + a1.w + a2.w + a3.w);
  }

  const int o0 = og * 128;
  const float* wb = wp + o0 * 8;
  const float* bb = bias + o0;
  float* yb = y + ((size_t)b * CDIM + o0) * HWDIM + s0;

  for (int i0 = 0; i0 < 128; i0 += 32) {
#pragma unroll 8
    for (int i = i0; i < i0 + 32; ++i) {
      const float4 w0 = *(const float4*)(wb + i * 8);
      const float4 w1 = *(const float4*)(wb + i * 8 + 4);
      const float wn[8] = {w0.x, w0.y, w0.z, w0.w, w1.x, w1.y, w1.z, w1.w};
      const float b0 = bb[i];
      float r[4] = {b0, b0, b0, b0};
#pragma unroll
      for (int n = 0; n < NH; ++n) {
        r[0] = fmaf(wn[n], Sv[n].x, r[0]);
        r[1] = fmaf(wn[n], Sv[n].y, r[1]);
        r[2] = fmaf(wn[n], Sv[n].z, r[2]);
        r[3] = fmaf(wn[n], Sv[n].w, r[3]);
      }
      *(float4*)(yb + (size_t)i * HWDIM) = make_float4(r[0], r[1], r[2], r[3]);
    }
    __syncthreads();   // cluster the 4 waves' write windows
  }
}

extern "C" void kernel_launch(void* const* d_in, const int* in_sizes, int n_in,
                              void* d_out, int out_size, void* d_ws, size_t ws_size,
                              hipStream_t stream) {
  const float* x     = (const float*)d_in[0];
  const float* wqkv  = (const float*)d_in[1];
  const float* wproj = (const float*)d_in[2];
  const float* bproj = (const float*)d_in[3];
  float* y = (float*)d_out;

  float* wvT = (float*)d_ws;                 // 4096 floats
  float* wp  = wvT + 4096;                   // 4096 floats
  float* pS  = wp + 4096;                    // 4 x 2 MB partial S

  prep_kernel<<<32, 256, 0, stream>>>(wqkv, wproj, wvT, wp);
  s_part_kernel<<<256, 256, 0, stream>>>(x, wvT, pS);
  y_kernel<<<256, 256, 0, stream>>>(pS, wp, bproj, y);
}